// Round 4
// baseline (1236.160 us; speedup 1.0000x reference)
//
#include <hip/hip_runtime.h>
#include <stdint.h>

typedef __bf16 bf16;
typedef __bf16 bf16x8 __attribute__((ext_vector_type(8)));
typedef __bf16 bf16x4 __attribute__((ext_vector_type(4)));
typedef float  f32x4  __attribute__((ext_vector_type(4)));
typedef _Float16 f16;

#define NB   4096   // sequence length
#define DB   1024   // model dim
#define HDV  64     // head dim
#define RV   64     // low rank
#define MB   16384  // B*N

// ---- dtype detection: are inputs f32 (reference dtype) or pre-cast bf16? ----
// If x is f32, reading it as u16 pairs: even halves are mantissa bits ->
// bf16-exponent uniform over [0,255] -> ~25% have exp >= 0xC0.
// If x is bf16 N(0,1), exponents <= ~0x82 -> zero hits.
__global__ void detect_dtype(const unsigned short* x, int* flag) {
  __shared__ int cnt;
  if (threadIdx.x == 0) cnt = 0;
  __syncthreads();
  int local = 0;
  for (int i = threadIdx.x; i < 8192; i += 256) {
    const int e = (x[i] >> 7) & 0xFF;
    if (e >= 0xC0) local++;
  }
  atomicAdd(&cnt, local);
  __syncthreads();
  if (threadIdx.x == 0) *flag = (cnt > 64) ? 1 : 0;  // 1 => inputs are f32
}

// normalize one tensor to bf16 (convert if flag, else copy). n % 8 == 0.
__global__ void to_bf16(const void* src, bf16* dst, const int* flag, int n) {
  const int i = (blockIdx.x * 256 + threadIdx.x) * 8;
  if (i >= n) return;
  if (*flag) {
    const float* s = (const float*)src + i;
    f32x4 a = *(const f32x4*)s;
    f32x4 b = *(const f32x4*)(s + 4);
    bf16x8 v;
    v[0]=(bf16)a[0]; v[1]=(bf16)a[1]; v[2]=(bf16)a[2]; v[3]=(bf16)a[3];
    v[4]=(bf16)b[0]; v[5]=(bf16)b[1]; v[6]=(bf16)b[2]; v[7]=(bf16)b[3];
    *(bf16x8*)(dst + i) = v;
  } else {
    *(uint4*)(dst + i) = *(const uint4*)((const bf16*)src + i);
  }
}

struct GemmArgs {
  const bf16* A;
  const bf16* B;
  void* C;
  const bf16* bias;    // col-indexed, nullable
  const int* oflag;    // if non-null and *oflag -> store C as f32, else bf16
  int M, N, K;
};

// C[m,n] = sum_k A[m,k]*B[n,k] (+bias[n]); fp32 accum.
// 128x128 tile, BK=64, 4 waves x (64x64 via 4x4 MFMA 16x16x32).
// Staging: global -> regs (uint4) -> ds_write_b128, XOR swizzle on the LDS
// write slot so fragment ds_read_b128 is conflict-free.
__global__ __launch_bounds__(256, 2) void gemm_nt(GemmArgs args) {
  const bf16* Bm = args.B;
  const int K = args.K, N = args.N;
  const int f32out = args.oflag ? *args.oflag : 0;

  __shared__ bf16 sA[128*64];
  __shared__ bf16 sB[128*64];

  const int t = threadIdx.x;
  const int lane = t & 63;
  const int wave = t >> 6;
  const int m0 = blockIdx.y * 128;
  const int n0 = blockIdx.x * 128;

  const bf16 *ga[4], *gb[4];
  int lslot[4];
#pragma unroll
  for (int i = 0; i < 4; ++i) {
    const int c   = i*256 + t;       // 16B chunk id within tile (1024 total)
    const int row = c >> 3;          // 8 chunks per 64-elem row
    const int j   = c & 7;
    ga[i] = args.A + (size_t)(m0 + row)*K + j*8;   // coalesced
    gb[i] = Bm     + (size_t)(n0 + row)*K + j*8;
    lslot[i] = row*8 + (j ^ (row & 7));            // swizzled LDS chunk
  }

  f32x4 acc[4][4] = {};

  const int wm = (wave & 1) * 64;
  const int wn = (wave >> 1) * 64;
  const int lr = lane & 15;
  const int quad = lane >> 4;

  uint4 ra[4], rb[4];
#pragma unroll
  for (int i = 0; i < 4; ++i) {
    ra[i] = *(const uint4*)(ga[i]);
    rb[i] = *(const uint4*)(gb[i]);
  }

  for (int kt = 0; kt < K; kt += 64) {
    __syncthreads();   // previous tile's readers done
#pragma unroll
    for (int i = 0; i < 4; ++i) {
      *(uint4*)(sA + lslot[i]*8) = ra[i];
      *(uint4*)(sB + lslot[i]*8) = rb[i];
    }
    __syncthreads();   // staged data visible
    if (kt + 64 < K) { // prefetch next tile into regs, overlaps MFMA
#pragma unroll
      for (int i = 0; i < 4; ++i) {
        ra[i] = *(const uint4*)(ga[i] + kt + 64);
        rb[i] = *(const uint4*)(gb[i] + kt + 64);
      }
    }
#pragma unroll
    for (int ks = 0; ks < 2; ++ks) {
      bf16x8 af[4], bv[4];
#pragma unroll
      for (int mi = 0; mi < 4; ++mi) {
        const int m = wm + mi*16 + lr;
        const int slot = m*8 + (((ks<<2) + quad) ^ (m & 7));
        af[mi] = *(const bf16x8*)(sA + slot*8);
      }
#pragma unroll
      for (int ni = 0; ni < 4; ++ni) {
        const int n = wn + ni*16 + lr;
        const int slot = n*8 + (((ks<<2) + quad) ^ (n & 7));
        bv[ni] = *(const bf16x8*)(sB + slot*8);
      }
#pragma unroll
      for (int mi = 0; mi < 4; ++mi)
#pragma unroll
        for (int ni = 0; ni < 4; ++ni)
          acc[mi][ni] = __builtin_amdgcn_mfma_f32_16x16x32_bf16(
              af[mi], bv[ni], acc[mi][ni], 0, 0, 0);
    }
  }

  // C/D layout: col = lane&15, row = quad*4 + reg  (m89/m91-verified)
#pragma unroll
  for (int ni = 0; ni < 4; ++ni) {
    const int col = n0 + wn + ni*16 + lr;
    const float bvv = args.bias ? (float)args.bias[col] : 0.0f;
#pragma unroll
    for (int mi = 0; mi < 4; ++mi) {
      const int row = m0 + wm + mi*16 + quad*4;
#pragma unroll
      for (int rg = 0; rg < 4; ++rg) {
        const float val = acc[mi][ni][rg] + bvv;
        const size_t idx = (size_t)(row+rg)*N + col;
        if (f32out) ((float*)args.C)[idx] = val;
        else        ((bf16*)args.C)[idx]  = (bf16)val;
      }
    }
  }
}

__global__ void zero_f4(float* p) {
  f32x4 z = {0.f, 0.f, 0.f, 0.f};
  ((f32x4*)p)[blockIdx.x*256 + threadIdx.x] = z;
}

// O[bh,r,d] += sum_n P[n,r]*X[b,h,n,d].  N split 8 ways (blockIdx.y),
// fp32 atomicAdd into pre-zeroed O. Each thread owns a 4x4 (r,d) tile.
__global__ __launch_bounds__(256, 4) void lowrank_proj(
    const bf16* __restrict__ P, const bf16* __restrict__ X,
    float* __restrict__ O) {
  const int bh = blockIdx.x;
  const int b = bh >> 4, h = bh & 15;
  const int seg = blockIdx.y;

  __shared__ bf16 sP[64*64];    // [n][r]
  __shared__ bf16 sX[64*64];    // [n][d]
  const int t = threadIdx.x;
  const int r0 = (t >> 4) * 4, d0 = (t & 15) * 4;
  float acc[4][4] = {};

  for (int c8 = 0; c8 < 8; ++c8) {
    const int nb = seg*512 + c8*64;
    *(uint4*)(sP + t*8)        = *(const uint4*)(P + (size_t)nb*RV + t*8);
    *(uint4*)(sP + 2048 + t*8) = *(const uint4*)(P + (size_t)nb*RV + 2048 + t*8);
#pragma unroll
    for (int i = 0; i < 2; ++i) {
      const int c = i*256 + t;
      const int row = c >> 3, k8 = c & 7;
      *(uint4*)(sX + row*64 + k8*8) =
          *(const uint4*)(X + ((size_t)b*NB + nb + row)*DB + h*64 + k8*8);
    }
    __syncthreads();
#pragma unroll 16
    for (int n = 0; n < 64; ++n) {
      bf16x4 pv = *(const bf16x4*)(sP + n*64 + r0);
      bf16x4 xv = *(const bf16x4*)(sX + n*64 + d0);
      float pf[4], xf[4];
#pragma unroll
      for (int i = 0; i < 4; ++i) { pf[i] = (float)pv[i]; xf[i] = (float)xv[i]; }
#pragma unroll
      for (int i = 0; i < 4; ++i)
#pragma unroll
        for (int j = 0; j < 4; ++j)
          acc[i][j] = fmaf(pf[i], xf[j], acc[i][j]);
    }
    __syncthreads();
  }
  float* Ob = O + bh*4096;
#pragma unroll
  for (int i = 0; i < 4; ++i)
#pragma unroll
    for (int j = 0; j < 4; ++j)
      atomicAdd(&Ob[(r0+i)*64 + d0 + j], acc[i][j]);
}

// One thread per Q row. AO may alias Q (thread reads its slice fully before
// writing it; blocks touch disjoint (row,col) regions).
__global__ __launch_bounds__(256, 2) void attn_low(
    const bf16* Q, const float* __restrict__ Klow,
    const float* __restrict__ Vlow, bf16* AO) {
  const int bh = blockIdx.y, b = bh >> 4, h = bh & 15;
  const int t = threadIdx.x;
  const int n = blockIdx.x * 256 + t;

  __shared__ float sK[64*64];
  __shared__ float sV[64*64];
  __shared__ f16   sS[64*256];

#pragma unroll
  for (int i = 0; i < 4; ++i) {
    const int idx = (i*256 + t)*4;
    *(f32x4*)(sK + idx) = *(const f32x4*)(Klow + bh*4096 + idx);
    *(f32x4*)(sV + idx) = *(const f32x4*)(Vlow + bh*4096 + idx);
  }
  __syncthreads();

  const bf16* qp = Q + ((size_t)b*NB + n)*DB + h*64;
  float q[64];
#pragma unroll
  for (int i = 0; i < 8; ++i) {
    bf16x8 v = *(const bf16x8*)(qp + i*8);
#pragma unroll
    for (int j = 0; j < 8; ++j) q[i*8+j] = (float)v[j];
  }

  float mx = -3.0e38f;
  for (int r = 0; r < 64; ++r) {
    float a = 0.0f;
#pragma unroll
    for (int d4 = 0; d4 < 16; ++d4) {
      f32x4 k4 = *(const f32x4*)(sK + r*64 + d4*4);
#pragma unroll
      for (int j = 0; j < 4; ++j) a = fmaf(q[d4*4+j], k4[j], a);
    }
    a *= 0.125f;
    sS[r*256 + t] = (f16)a;
    mx = fmaxf(mx, a);
  }

  float o[64];
#pragma unroll
  for (int i = 0; i < 64; ++i) o[i] = 0.0f;
  float sum = 0.0f;
  for (int r = 0; r < 64; ++r) {
    const float p = __expf((float)sS[r*256 + t] - mx);
    sum += p;
#pragma unroll
    for (int d4 = 0; d4 < 16; ++d4) {
      f32x4 v4 = *(const f32x4*)(sV + r*64 + d4*4);
#pragma unroll
      for (int j = 0; j < 4; ++j) o[d4*4+j] = fmaf(p, v4[j], o[d4*4+j]);
    }
  }
  const float inv = 1.0f / sum;
  bf16* op = AO + ((size_t)b*NB + n)*DB + h*64;
#pragma unroll
  for (int i = 0; i < 8; ++i) {
    bf16x8 v;
#pragma unroll
    for (int j = 0; j < 8; ++j) v[j] = (bf16)(o[i*8+j] * inv);
    *(bf16x8*)(op + i*8) = v;
  }
}

static inline int cvt_blocks(int n) { return (n/8 + 255) / 256; }

extern "C" void kernel_launch(void* const* d_in, const int* in_sizes, int n_in,
                              void* d_out, int out_size, void* d_ws, size_t ws_size,
                              hipStream_t stream) {
  char* ws = (char*)d_ws;
  const size_t MiB = 1024*1024;
  const size_t need = 112*MiB;
  const bool norm = (ws_size >= need);

  GemmArgs ga;
  ga.M = MB; ga.N = DB; ga.K = DB; ga.bias = nullptr; ga.oflag = nullptr;

  if (norm) {
    int*   flag = (int*)ws;
    float* Klow = (float*)(ws + 1*MiB);
    float* Vlow = (float*)(ws + 2*MiB);
    bf16*  Wqb  = (bf16*)(ws + 3*MiB);
    bf16*  Wkb  = (bf16*)(ws + 5*MiB);
    bf16*  Wvb  = (bf16*)(ws + 7*MiB);
    bf16*  Wob  = (bf16*)(ws + 9*MiB);
    bf16*  bob  = (bf16*)(ws + 11*MiB);
    bf16*  Eb   = (bf16*)(ws + 12*MiB);
    bf16*  Fmb  = (bf16*)(ws + 13*MiB);
    bf16*  xb   = (bf16*)(ws + 16*MiB);
    bf16*  S0   = (bf16*)(ws + 48*MiB);   // Q, then AO in-place
    bf16*  S1   = (bf16*)(ws + 80*MiB);   // K, then V

    detect_dtype<<<1, 256, 0, stream>>>((const unsigned short*)d_in[0], flag);
    to_bf16<<<cvt_blocks(16777216), 256, 0, stream>>>(d_in[0], xb,  flag, 16777216);
    to_bf16<<<cvt_blocks(1048576),  256, 0, stream>>>(d_in[1], Wqb, flag, 1048576);
    to_bf16<<<cvt_blocks(1048576),  256, 0, stream>>>(d_in[2], Wkb, flag, 1048576);
    to_bf16<<<cvt_blocks(1048576),  256, 0, stream>>>(d_in[3], Wvb, flag, 1048576);
    to_bf16<<<cvt_blocks(1048576),  256, 0, stream>>>(d_in[4], Wob, flag, 1048576);
    to_bf16<<<cvt_blocks(1024),     256, 0, stream>>>(d_in[5], bob, flag, 1024);
    to_bf16<<<cvt_blocks(262144),   256, 0, stream>>>(d_in[6], Eb,  flag, 262144);
    to_bf16<<<cvt_blocks(262144),   256, 0, stream>>>(d_in[7], Fmb, flag, 262144);

    zero_f4<<<dim3(512), 256, 0, stream>>>(Klow);   // zeros Klow+Vlow (2 MiB)

    ga.A = xb;
    ga.B = Wkb; ga.C = S1;
    gemm_nt<<<dim3(8, 128), 256, 0, stream>>>(ga);
    lowrank_proj<<<dim3(64, 8), 256, 0, stream>>>(Eb, S1, Klow);

    ga.B = Wvb;
    gemm_nt<<<dim3(8, 128), 256, 0, stream>>>(ga);
    lowrank_proj<<<dim3(64, 8), 256, 0, stream>>>(Fmb, S1, Vlow);

    ga.B = Wqb; ga.C = S0;
    gemm_nt<<<dim3(8, 128), 256, 0, stream>>>(ga);

    attn_low<<<dim3(16, 64), 256, 0, stream>>>(S0, Klow, Vlow, S0);

    GemmArgs oa;
    oa.A = S0; oa.B = Wob; oa.C = d_out; oa.bias = bob; oa.oflag = flag;
    oa.M = MB; oa.N = DB; oa.K = DB;
    gemm_nt<<<dim3(8, 128), 256, 0, stream>>>(oa);
  } else {
    // fallback: assume bf16 inputs, 66 MiB layout
    bf16*  S0   = (bf16*)(ws);
    bf16*  S1   = (bf16*)(ws + 32*MiB);
    float* Klow = (float*)(ws + 64*MiB);
    float* Vlow = Klow + 262144;

    zero_f4<<<dim3(512), 256, 0, stream>>>(Klow);

    ga.A = (const bf16*)d_in[0];
    ga.B = (const bf16*)d_in[2]; ga.C = S1;
    gemm_nt<<<dim3(8, 128), 256, 0, stream>>>(ga);
    lowrank_proj<<<dim3(64, 8), 256, 0, stream>>>((const bf16*)d_in[6], S1, Klow);

    ga.B = (const bf16*)d_in[3];
    gemm_nt<<<dim3(8, 128), 256, 0, stream>>>(ga);
    lowrank_proj<<<dim3(64, 8), 256, 0, stream>>>((const bf16*)d_in[7], S1, Vlow);

    ga.B = (const bf16*)d_in[1]; ga.C = S0;
    gemm_nt<<<dim3(8, 128), 256, 0, stream>>>(ga);

    attn_low<<<dim3(16, 64), 256, 0, stream>>>(S0, Klow, Vlow, S0);

    GemmArgs oa;
    oa.A = S0; oa.B = (const bf16*)d_in[4]; oa.C = d_out;
    oa.bias = (const bf16*)d_in[5]; oa.oflag = nullptr;
    oa.M = MB; oa.N = DB; oa.K = DB;
    gemm_nt<<<dim3(8, 128), 256, 0, stream>>>(oa);
  }
}

// Round 5
// 846.965 us; speedup vs baseline: 1.4595x; 1.4595x over previous
//
#include <hip/hip_runtime.h>
#include <stdint.h>

typedef __bf16 bf16;
typedef __bf16 bf16x8 __attribute__((ext_vector_type(8)));
typedef __bf16 bf16x4 __attribute__((ext_vector_type(4)));
typedef float  f32x4  __attribute__((ext_vector_type(4)));

#define NB   4096   // sequence length
#define DB   1024   // model dim
#define RV   64     // low rank
#define MB   16384  // B*N

// ---- dtype detection (unchanged from round 4 -- it works) ----
__global__ void detect_dtype(const unsigned short* x, int* flag) {
  __shared__ int cnt;
  if (threadIdx.x == 0) cnt = 0;
  __syncthreads();
  int local = 0;
  for (int i = threadIdx.x; i < 8192; i += 256) {
    const int e = (x[i] >> 7) & 0xFF;
    if (e >= 0xC0) local++;
  }
  atomicAdd(&cnt, local);
  __syncthreads();
  if (threadIdx.x == 0) *flag = (cnt > 64) ? 1 : 0;  // 1 => inputs are f32
}

__global__ void to_bf16(const void* src, bf16* dst, const int* flag, int n) {
  const int i = (blockIdx.x * 256 + threadIdx.x) * 8;
  if (i >= n) return;
  if (*flag) {
    const float* s = (const float*)src + i;
    f32x4 a = *(const f32x4*)s;
    f32x4 b = *(const f32x4*)(s + 4);
    bf16x8 v;
    v[0]=(bf16)a[0]; v[1]=(bf16)a[1]; v[2]=(bf16)a[2]; v[3]=(bf16)a[3];
    v[4]=(bf16)b[0]; v[5]=(bf16)b[1]; v[6]=(bf16)b[2]; v[7]=(bf16)b[3];
    *(bf16x8*)(dst + i) = v;
  } else {
    *(uint4*)(dst + i) = *(const uint4*)((const bf16*)src + i);
  }
}

__global__ void cvt_f32_bf16(const float* __restrict__ src, bf16* __restrict__ dst, int n) {
  const int i = (blockIdx.x * 256 + threadIdx.x) * 8;
  if (i >= n) return;
  f32x4 a = *(const f32x4*)(src + i);
  f32x4 b = *(const f32x4*)(src + i + 4);
  bf16x8 v;
  v[0]=(bf16)a[0]; v[1]=(bf16)a[1]; v[2]=(bf16)a[2]; v[3]=(bf16)a[3];
  v[4]=(bf16)b[0]; v[5]=(bf16)b[1]; v[6]=(bf16)b[2]; v[7]=(bf16)b[3];
  *(bf16x8*)(dst + i) = v;
}

__global__ void zero_f4(float* p) {
  f32x4 z = {0.f, 0.f, 0.f, 0.f};
  ((f32x4*)p)[blockIdx.x*256 + threadIdx.x] = z;
}

struct GemmArgs {
  const bf16* A;
  const bf16* B;
  void* C;
  const bf16* bias;    // col-indexed, nullable
  const int* oflag;    // runtime f32-out flag (nullable)
  int force_f32;       // compile-side f32-out override
  int M, N, K;
};

// C[m,n] = sum_k A[m,k]*B[n,k] (+bias[n]); fp32 accum.
// 128x128 tile, BK=64, 4 waves x (64x64 via 4x4 MFMA 16x16x32).
// K-loop identical to round 4 (verified PASS). New this round:
//  - XCD swizzle (full grids only): XCD k owns m-tiles k*16..k*16+15 so the
//    4 MiB A slab stays resident in that XCD's L2 -> FETCH ~8x down.
//  - Coalesced epilogue: acc staged to LDS f32 (dword-XOR swizzle), read back
//    row-major, dwordx4/x2 stores -> WRITE ~18x down.
__global__ __launch_bounds__(256, 2) void gemm_nt(GemmArgs args) {
  const bf16* Bm = args.B;
  const int K = args.K, N = args.N;
  const int f32out = args.force_f32 | (args.oflag ? *args.oflag : 0);

  __shared__ __align__(16) char smem[32768];
  bf16*  sA = (bf16*)smem;              // 16 KiB
  bf16*  sB = (bf16*)(smem + 16384);    // 16 KiB
  float* sE = (float*)smem;             // epilogue reuse: 128x64 f32 = 32 KiB

  const int t = threadIdx.x;
  const int lane = t & 63;
  const int wave = t >> 6;

  int bx = blockIdx.x, by = blockIdx.y;
  if (gridDim.y == 128) {               // XCD-locality remap (full-size GEMMs)
    const int l = by*8 + bx;            // linear dispatch id (x fastest)
    const int xcd = l & 7, s = l >> 3;  // dispatch round-robins XCDs [heuristic]
    by = xcd*16 + (s & 15);             // 16 m-tiles per XCD -> 4 MiB A slab
    bx = s >> 4;
  }
  const int m0 = by * 128;
  const int n0 = bx * 128;

  const bf16 *ga[4], *gb[4];
  int lslot[4];
#pragma unroll
  for (int i = 0; i < 4; ++i) {
    const int c   = i*256 + t;       // 16B chunk id within tile (1024 total)
    const int row = c >> 3;          // 8 chunks per 64-elem row
    const int j   = c & 7;
    ga[i] = args.A + (size_t)(m0 + row)*K + j*8;   // coalesced
    gb[i] = Bm     + (size_t)(n0 + row)*K + j*8;
    lslot[i] = row*8 + (j ^ (row & 7));            // swizzled LDS chunk
  }

  f32x4 acc[4][4] = {};

  const int wm = (wave & 1) * 64;
  const int wn = (wave >> 1) * 64;
  const int lr = lane & 15;
  const int quad = lane >> 4;

  uint4 ra[4], rb[4];
#pragma unroll
  for (int i = 0; i < 4; ++i) {
    ra[i] = *(const uint4*)(ga[i]);
    rb[i] = *(const uint4*)(gb[i]);
  }

  for (int kt = 0; kt < K; kt += 64) {
    __syncthreads();   // previous tile's readers done
#pragma unroll
    for (int i = 0; i < 4; ++i) {
      *(uint4*)(sA + lslot[i]*8) = ra[i];
      *(uint4*)(sB + lslot[i]*8) = rb[i];
    }
    __syncthreads();   // staged data visible
    if (kt + 64 < K) { // prefetch next tile into regs, overlaps MFMA
#pragma unroll
      for (int i = 0; i < 4; ++i) {
        ra[i] = *(const uint4*)(ga[i] + kt + 64);
        rb[i] = *(const uint4*)(gb[i] + kt + 64);
      }
    }
#pragma unroll
    for (int ks = 0; ks < 2; ++ks) {
      bf16x8 af[4], bv[4];
#pragma unroll
      for (int mi = 0; mi < 4; ++mi) {
        const int m = wm + mi*16 + lr;
        const int slot = m*8 + (((ks<<2) + quad) ^ (m & 7));
        af[mi] = *(const bf16x8*)(sA + slot*8);
      }
#pragma unroll
      for (int ni = 0; ni < 4; ++ni) {
        const int n = wn + ni*16 + lr;
        const int slot = n*8 + (((ks<<2) + quad) ^ (n & 7));
        bv[ni] = *(const bf16x8*)(sB + slot*8);
      }
#pragma unroll
      for (int mi = 0; mi < 4; ++mi)
#pragma unroll
        for (int ni = 0; ni < 4; ++ni)
          acc[mi][ni] = __builtin_amdgcn_mfma_f32_16x16x32_bf16(
              af[mi], bv[ni], acc[mi][ni], 0, 0, 0);
    }
  }

  // ---- coalesced epilogue: 2 half-tile passes (cols p*64..p*64+63) ----
  // MFMA C/D layout: col = lane&15, row = quad*4 + reg (m89/m91-verified).
  // LDS addr: row*64 + (d ^ ((row&15)*4)) -> write: 16 banks/quad-pair,
  // 2 lanes/bank (free); read: b128 of 4 orig-contiguous dwords.
#pragma unroll
  for (int p = 0; p < 2; ++p) {
    __syncthreads();                 // prior readers (MFMA or pass0) done
    if (wn == p*64) {
#pragma unroll
      for (int ni = 0; ni < 4; ++ni) {
        const int cl = ni*16 + lr;   // local col 0..63
        const int colg = n0 + p*64 + cl;
        const float bvv = args.bias ? (float)args.bias[colg] : 0.0f;
#pragma unroll
        for (int mi = 0; mi < 4; ++mi) {
          const int rbase = wm + mi*16 + quad*4;
#pragma unroll
          for (int rg = 0; rg < 4; ++rg) {
            const int row = rbase + rg;
            sE[row*64 + (cl ^ ((row & 15)*4))] = acc[mi][ni][rg] + bvv;
          }
        }
      }
    }
    __syncthreads();                 // staged half-tile visible
#pragma unroll
    for (int i = 0; i < 8; ++i) {
      const int c = i*256 + t;       // 2048 chunks of 4 f32
      const int row = c >> 4, ch = c & 15;
      const int d0 = ch*4;
      f32x4 v = *(const f32x4*)(sE + row*64 + (d0 ^ ((row & 15)*4)));
      const size_t base = (size_t)(m0+row)*N + n0 + p*64 + d0;
      if (f32out) {
        *(f32x4*)((float*)args.C + base) = v;
      } else {
        bf16x4 w;
        w[0]=(bf16)v[0]; w[1]=(bf16)v[1]; w[2]=(bf16)v[2]; w[3]=(bf16)v[3];
        *(bf16x4*)((bf16*)args.C + base) = w;
      }
    }
  }
}

// xE[b,r,d] += sum_n P[n,r] * xb[b,n,d-slice].  Grid (b*16+dtile, seg8, {E,Fm}).
// fp32 atomicAdd into pre-zeroed output; each thread owns a 4x4 (r,d) tile.
__global__ __launch_bounds__(256, 4) void lowrank_xe(
    const bf16* __restrict__ E, const bf16* __restrict__ Fm,
    const bf16* __restrict__ xb,
    float* __restrict__ xEf, float* __restrict__ xFf) {
  const int bx = blockIdx.x;
  const int b = bx >> 4, dt = bx & 15;
  const int seg = blockIdx.y;
  const bf16* P = blockIdx.z ? Fm : E;
  float* O      = blockIdx.z ? xFf : xEf;

  __shared__ bf16 sP[4096];     // [n][r] 64x64
  __shared__ bf16 sX[4096];     // [n][d] 64x64
  const int t = threadIdx.x;
  const int r0 = (t >> 4) * 4, d0 = (t & 15) * 4;
  float acc[4][4] = {};

  for (int c8 = 0; c8 < 8; ++c8) {
    const int nb = seg*512 + c8*64;
    *(uint4*)(sP + t*8)        = *(const uint4*)(P + (size_t)nb*RV + t*8);
    *(uint4*)(sP + 2048 + t*8) = *(const uint4*)(P + (size_t)nb*RV + 2048 + t*8);
#pragma unroll
    for (int i = 0; i < 2; ++i) {
      const int c = i*256 + t;
      const int row = c >> 3, k8 = c & 7;
      *(uint4*)(sX + row*64 + k8*8) =
          *(const uint4*)(xb + ((size_t)b*NB + nb + row)*DB + dt*64 + k8*8);
    }
    __syncthreads();
#pragma unroll 16
    for (int n = 0; n < 64; ++n) {
      bf16x4 pv = *(const bf16x4*)(sP + n*64 + r0);
      bf16x4 xv = *(const bf16x4*)(sX + n*64 + d0);
      float pf[4], xf[4];
#pragma unroll
      for (int i = 0; i < 4; ++i) { pf[i] = (float)pv[i]; xf[i] = (float)xv[i]; }
#pragma unroll
      for (int i = 0; i < 4; ++i)
#pragma unroll
        for (int j = 0; j < 4; ++j)
          acc[i][j] = fmaf(pf[i], xf[j], acc[i][j]);
    }
    __syncthreads();
  }
  float* Ob = O + ((size_t)b*64)*DB + dt*64;
#pragma unroll
  for (int i = 0; i < 4; ++i)
#pragma unroll
    for (int j = 0; j < 4; ++j)
      atomicAdd(&Ob[(size_t)(r0+i)*DB + d0 + j], acc[i][j]);
}

// One thread per Q row. Klow/Vlow layout: [(b*64+r)*1024 + h*64 + hd] (f32).
// AO may alias Q (each thread reads its whole slice before writing it).
__global__ __launch_bounds__(256, 2) void attn_low(
    const bf16* Q, const float* __restrict__ Klow,
    const float* __restrict__ Vlow, bf16* AO) {
  const int bh = blockIdx.y, b = bh >> 4, h = bh & 15;
  const int t = threadIdx.x;
  const int n = blockIdx.x * 256 + t;

  __shared__ float sK[64*64];
  __shared__ float sV[64*64];
  __shared__ _Float16 sS[64*256];

  {
    const float* kb = Klow + (size_t)(b*64)*DB + h*64;
    const float* vb = Vlow + (size_t)(b*64)*DB + h*64;
    const int r = t >> 2, c0 = (t & 3) * 16;
#pragma unroll
    for (int i = 0; i < 4; ++i) {
      *(f32x4*)(sK + r*64 + c0 + i*4) = *(const f32x4*)(kb + (size_t)r*DB + c0 + i*4);
      *(f32x4*)(sV + r*64 + c0 + i*4) = *(const f32x4*)(vb + (size_t)r*DB + c0 + i*4);
    }
  }
  __syncthreads();

  const bf16* qp = Q + ((size_t)b*NB + n)*DB + h*64;
  float q[64];
#pragma unroll
  for (int i = 0; i < 8; ++i) {
    bf16x8 v = *(const bf16x8*)(qp + i*8);
#pragma unroll
    for (int j = 0; j < 8; ++j) q[i*8+j] = (float)v[j];
  }

  float mx = -3.0e38f;
  for (int r = 0; r < 64; ++r) {
    float a = 0.0f;
#pragma unroll
    for (int d4 = 0; d4 < 16; ++d4) {
      f32x4 k4 = *(const f32x4*)(sK + r*64 + d4*4);
#pragma unroll
      for (int j = 0; j < 4; ++j) a = fmaf(q[d4*4+j], k4[j], a);
    }
    a *= 0.125f;
    sS[r*256 + t] = (_Float16)a;
    mx = fmaxf(mx, a);
  }

  float o[64];
#pragma unroll
  for (int i = 0; i < 64; ++i) o[i] = 0.0f;
  float sum = 0.0f;
  for (int r = 0; r < 64; ++r) {
    const float p = __expf((float)sS[r*256 + t] - mx);
    sum += p;
#pragma unroll
    for (int d4 = 0; d4 < 16; ++d4) {
      f32x4 v4 = *(const f32x4*)(sV + r*64 + d4*4);
#pragma unroll
      for (int j = 0; j < 4; ++j) o[d4*4+j] = fmaf(p, v4[j], o[d4*4+j]);
    }
  }
  const float inv = 1.0f / sum;
  bf16* op = AO + ((size_t)b*NB + n)*DB + h*64;
#pragma unroll
  for (int i = 0; i < 8; ++i) {
    bf16x8 v;
#pragma unroll
    for (int j = 0; j < 8; ++j) v[j] = (bf16)(o[i*8+j] * inv);
    *(bf16x8*)(op + i*8) = v;
  }
}

static inline int cvt_blocks(int n) { return (n/8 + 255) / 256; }

extern "C" void kernel_launch(void* const* d_in, const int* in_sizes, int n_in,
                              void* d_out, int out_size, void* d_ws, size_t ws_size,
                              hipStream_t stream) {
  char* ws = (char*)d_ws;
  const size_t MiB = 1024*1024;
  // ws_size >= 112 MiB proven by round-4 pass (norm path ran). Layout: 84 MiB.
  int*   flag = (int*)ws;
  float* Klow = (float*)(ws + 1*MiB);     // 1 MiB  (256x1024 f32)
  float* Vlow = (float*)(ws + 2*MiB);     // 1 MiB
  float* xEf  = (float*)(ws + 3*MiB);     // 1 MiB  (fp32 accum, pre-zeroed)
  float* xFf  = (float*)(ws + 4*MiB);     // 1 MiB  (contiguous with xEf)
  bf16*  xEb  = (bf16*)(ws + 5*MiB);      // 512 KiB (contig with xFb)
  bf16*  xFb  = (bf16*)(ws + 5*MiB + 512*1024);
  bf16*  Wqb  = (bf16*)(ws + 7*MiB);
  bf16*  Wkb  = (bf16*)(ws + 9*MiB);
  bf16*  Wvb  = (bf16*)(ws + 11*MiB);
  bf16*  Wob  = (bf16*)(ws + 13*MiB);
  bf16*  bob  = (bf16*)(ws + 15*MiB);
  bf16*  Eb   = (bf16*)(ws + 16*MiB);
  bf16*  Fmb  = (bf16*)(ws + 17*MiB);
  bf16*  xb   = (bf16*)(ws + 20*MiB);     // 32 MiB
  bf16*  S0   = (bf16*)(ws + 52*MiB);     // 32 MiB: Q, then AO in-place

  detect_dtype<<<1, 256, 0, stream>>>((const unsigned short*)d_in[0], flag);
  to_bf16<<<cvt_blocks(16777216), 256, 0, stream>>>(d_in[0], xb,  flag, 16777216);
  to_bf16<<<cvt_blocks(1048576),  256, 0, stream>>>(d_in[1], Wqb, flag, 1048576);
  to_bf16<<<cvt_blocks(1048576),  256, 0, stream>>>(d_in[2], Wkb, flag, 1048576);
  to_bf16<<<cvt_blocks(1048576),  256, 0, stream>>>(d_in[3], Wvb, flag, 1048576);
  to_bf16<<<cvt_blocks(1048576),  256, 0, stream>>>(d_in[4], Wob, flag, 1048576);
  to_bf16<<<cvt_blocks(1024),     256, 0, stream>>>(d_in[5], bob, flag, 1024);
  to_bf16<<<cvt_blocks(262144),   256, 0, stream>>>(d_in[6], Eb,  flag, 262144);
  to_bf16<<<cvt_blocks(262144),   256, 0, stream>>>(d_in[7], Fmb, flag, 262144);

  zero_f4<<<dim3(512), 256, 0, stream>>>(xEf);   // zeros xEf+xFf (2 MiB)

  // xE = E^T x, xF = Fm^T x   (the Linformer algebra that deletes K/V GEMMs)
  lowrank_xe<<<dim3(64, 8, 2), 256, 0, stream>>>(Eb, Fmb, xb, xEf, xFf);
  cvt_f32_bf16<<<dim3(256), 256, 0, stream>>>(xEf, xEb, 524288);  // xEf+xFf -> xEb+xFb

  GemmArgs ka;                       // Klow = xE @ Wk^T   (M=256, tiny)
  ka.A = xEb; ka.B = Wkb; ka.C = Klow; ka.bias = nullptr;
  ka.oflag = nullptr; ka.force_f32 = 1;
  ka.M = 256; ka.N = DB; ka.K = DB;
  gemm_nt<<<dim3(8, 2), 256, 0, stream>>>(ka);
  ka.A = xFb; ka.B = Wvb; ka.C = Vlow;   // Vlow = xF @ Wv^T
  gemm_nt<<<dim3(8, 2), 256, 0, stream>>>(ka);

  GemmArgs qa;                       // Q = x @ Wq^T
  qa.A = xb; qa.B = Wqb; qa.C = S0; qa.bias = nullptr;
  qa.oflag = nullptr; qa.force_f32 = 0;
  qa.M = MB; qa.N = DB; qa.K = DB;
  gemm_nt<<<dim3(8, 128), 256, 0, stream>>>(qa);

  attn_low<<<dim3(16, 64), 256, 0, stream>>>(S0, Klow, Vlow, S0);

  GemmArgs oa;                       // out = AO @ Wo^T + bo
  oa.A = S0; oa.B = Wob; oa.C = d_out; oa.bias = bob;
  oa.oflag = flag; oa.force_f32 = 0;
  oa.M = MB; oa.N = DB; oa.K = DB;
  gemm_nt<<<dim3(8, 128), 256, 0, stream>>>(oa);
}

// Round 6
// 773.449 us; speedup vs baseline: 1.5982x; 1.0951x over previous
//
#include <hip/hip_runtime.h>
#include <stdint.h>

typedef __bf16 bf16;
typedef __bf16 bf16x8 __attribute__((ext_vector_type(8)));
typedef __bf16 bf16x4 __attribute__((ext_vector_type(4)));
typedef float  f32x4  __attribute__((ext_vector_type(4)));

#define NB   4096   // sequence length
#define DB   1024   // model dim
#define RV   64     // low rank
#define MB   16384  // B*N

// ---- dtype detection (verified working, rounds 4-5) ----
__global__ void detect_dtype(const unsigned short* x, int* flag) {
  __shared__ int cnt;
  if (threadIdx.x == 0) cnt = 0;
  __syncthreads();
  int local = 0;
  for (int i = threadIdx.x; i < 8192; i += 256) {
    const int e = (x[i] >> 7) & 0xFF;
    if (e >= 0xC0) local++;
  }
  atomicAdd(&cnt, local);
  __syncthreads();
  if (threadIdx.x == 0) *flag = (cnt > 64) ? 1 : 0;  // 1 => inputs are f32
}

// ---- one dispatch converts all 8 input tensors ----
struct CvtArgs {
  const void* src[8];
  bf16* dst[8];
  int n[8];
  int off[9];   // block-range prefix sums
};
__global__ void to_bf16_multi(CvtArgs a, const int* __restrict__ flag) {
  const int blk = blockIdx.x;
  int seg = 0;
#pragma unroll
  for (int s = 1; s < 8; ++s) seg += (blk >= a.off[s]);
  const int i = (blk - a.off[seg]) * 2048 + threadIdx.x * 8;
  if (i >= a.n[seg]) return;
  bf16* dst = a.dst[seg];
  if (*flag) {
    const float* s = (const float*)a.src[seg] + i;
    f32x4 x0 = *(const f32x4*)s;
    f32x4 x1 = *(const f32x4*)(s + 4);
    bf16x8 v;
    v[0]=(bf16)x0[0]; v[1]=(bf16)x0[1]; v[2]=(bf16)x0[2]; v[3]=(bf16)x0[3];
    v[4]=(bf16)x1[0]; v[5]=(bf16)x1[1]; v[6]=(bf16)x1[2]; v[7]=(bf16)x1[3];
    *(bf16x8*)(dst + i) = v;
  } else {
    *(uint4*)(dst + i) = *(const uint4*)((const bf16*)a.src[seg] + i);
  }
}

__global__ void cvt_f32_bf16(const float* __restrict__ src, bf16* __restrict__ dst, int n) {
  const int i = (blockIdx.x * 256 + threadIdx.x) * 8;
  if (i >= n) return;
  f32x4 a = *(const f32x4*)(src + i);
  f32x4 b = *(const f32x4*)(src + i + 4);
  bf16x8 v;
  v[0]=(bf16)a[0]; v[1]=(bf16)a[1]; v[2]=(bf16)a[2]; v[3]=(bf16)a[3];
  v[4]=(bf16)b[0]; v[5]=(bf16)b[1]; v[6]=(bf16)b[2]; v[7]=(bf16)b[3];
  *(bf16x8*)(dst + i) = v;
}

__global__ void zero_f4(float* p) {
  f32x4 z = {0.f, 0.f, 0.f, 0.f};
  ((f32x4*)p)[blockIdx.x*256 + threadIdx.x] = z;
}

struct GemmArgs {
  const bf16* A;
  const bf16* B;
  void* C;
  const bf16* bias;
  const int* oflag;    // runtime f32-out flag (nullable)
  int force_f32;
  int M, N, K;
};

// C[m,n] = sum_k A[m,k]*B[n,k] (+bias[n]); fp32 accum. 128x128 tile, BK=64.
// XCD remap (full grids): n-fastest within each XCD's 16-m-tile slab so the
// ~64 concurrent blocks/XCD touch A 2 MiB + B 2 MiB = 4 MiB = L2 capacity.
__global__ __launch_bounds__(256, 2) void gemm_nt(GemmArgs args) {
  const bf16* Bm = args.B;
  const int K = args.K, N = args.N;
  const int f32out = args.force_f32 | (args.oflag ? *args.oflag : 0);

  __shared__ __align__(16) char smem[32768];
  bf16*  sA = (bf16*)smem;
  bf16*  sB = (bf16*)(smem + 16384);
  float* sE = (float*)smem;   // epilogue reuse

  const int t = threadIdx.x;
  const int lane = t & 63;
  const int wave = t >> 6;

  int bx = blockIdx.x, by = blockIdx.y;
  if (gridDim.y == 128) {
    const int l = by*8 + bx;
    const int xcd = l & 7, s = l >> 3;   // dispatch round-robins XCDs
    by = xcd*16 + (s >> 3);              // n-fastest: 8m x 8n concurrent
    bx = s & 7;
  }
  const int m0 = by * 128;
  const int n0 = bx * 128;

  const bf16 *ga[4], *gb[4];
  int lslot[4];
#pragma unroll
  for (int i = 0; i < 4; ++i) {
    const int c   = i*256 + t;
    const int row = c >> 3;
    const int j   = c & 7;
    ga[i] = args.A + (size_t)(m0 + row)*K + j*8;
    gb[i] = Bm     + (size_t)(n0 + row)*K + j*8;
    lslot[i] = row*8 + (j ^ (row & 7));
  }

  f32x4 acc[4][4] = {};

  const int wm = (wave & 1) * 64;
  const int wn = (wave >> 1) * 64;
  const int lr = lane & 15;
  const int quad = lane >> 4;

  uint4 ra[4], rb[4];
#pragma unroll
  for (int i = 0; i < 4; ++i) {
    ra[i] = *(const uint4*)(ga[i]);
    rb[i] = *(const uint4*)(gb[i]);
  }

  for (int kt = 0; kt < K; kt += 64) {
    __syncthreads();
#pragma unroll
    for (int i = 0; i < 4; ++i) {
      *(uint4*)(sA + lslot[i]*8) = ra[i];
      *(uint4*)(sB + lslot[i]*8) = rb[i];
    }
    __syncthreads();
    if (kt + 64 < K) {
#pragma unroll
      for (int i = 0; i < 4; ++i) {
        ra[i] = *(const uint4*)(ga[i] + kt + 64);
        rb[i] = *(const uint4*)(gb[i] + kt + 64);
      }
    }
#pragma unroll
    for (int ks = 0; ks < 2; ++ks) {
      bf16x8 af[4], bv[4];
#pragma unroll
      for (int mi = 0; mi < 4; ++mi) {
        const int m = wm + mi*16 + lr;
        const int slot = m*8 + (((ks<<2) + quad) ^ (m & 7));
        af[mi] = *(const bf16x8*)(sA + slot*8);
      }
#pragma unroll
      for (int ni = 0; ni < 4; ++ni) {
        const int n = wn + ni*16 + lr;
        const int slot = n*8 + (((ks<<2) + quad) ^ (n & 7));
        bv[ni] = *(const bf16x8*)(sB + slot*8);
      }
#pragma unroll
      for (int mi = 0; mi < 4; ++mi)
#pragma unroll
        for (int ni = 0; ni < 4; ++ni)
          acc[mi][ni] = __builtin_amdgcn_mfma_f32_16x16x32_bf16(
              af[mi], bv[ni], acc[mi][ni], 0, 0, 0);
    }
  }

  // coalesced epilogue (verified round 5)
#pragma unroll
  for (int p = 0; p < 2; ++p) {
    __syncthreads();
    if (wn == p*64) {
#pragma unroll
      for (int ni = 0; ni < 4; ++ni) {
        const int cl = ni*16 + lr;
        const int colg = n0 + p*64 + cl;
        const float bvv = args.bias ? (float)args.bias[colg] : 0.0f;
#pragma unroll
        for (int mi = 0; mi < 4; ++mi) {
          const int rbase = wm + mi*16 + quad*4;
#pragma unroll
          for (int rg = 0; rg < 4; ++rg) {
            const int row = rbase + rg;
            sE[row*64 + (cl ^ ((row & 15)*4))] = acc[mi][ni][rg] + bvv;
          }
        }
      }
    }
    __syncthreads();
#pragma unroll
    for (int i = 0; i < 8; ++i) {
      const int c = i*256 + t;
      const int row = c >> 4, ch = c & 15;
      const int d0 = ch*4;
      f32x4 v = *(const f32x4*)(sE + row*64 + (d0 ^ ((row & 15)*4)));
      const size_t base = (size_t)(m0+row)*N + n0 + p*64 + d0;
      if (f32out) {
        *(f32x4*)((float*)args.C + base) = v;
      } else {
        bf16x4 w;
        w[0]=(bf16)v[0]; w[1]=(bf16)v[1]; w[2]=(bf16)v[2]; w[3]=(bf16)v[3];
        *(bf16x4*)((bf16*)args.C + base) = w;
      }
    }
  }
}

// xE[b,r,d] += sum_n P[n,r] * xb[b,n,dslice] (verified round 5)
__global__ __launch_bounds__(256, 4) void lowrank_xe(
    const bf16* __restrict__ E, const bf16* __restrict__ Fm,
    const bf16* __restrict__ xb,
    float* __restrict__ xEf, float* __restrict__ xFf) {
  const int bx = blockIdx.x;
  const int b = bx >> 4, dt = bx & 15;
  const int seg = blockIdx.y;
  const bf16* P = blockIdx.z ? Fm : E;
  float* O      = blockIdx.z ? xFf : xEf;

  __shared__ bf16 sP[4096];
  __shared__ bf16 sX[4096];
  const int t = threadIdx.x;
  const int r0 = (t >> 4) * 4, d0 = (t & 15) * 4;
  float acc[4][4] = {};

  for (int c8 = 0; c8 < 8; ++c8) {
    const int nb = seg*512 + c8*64;
    *(uint4*)(sP + t*8)        = *(const uint4*)(P + (size_t)nb*RV + t*8);
    *(uint4*)(sP + 2048 + t*8) = *(const uint4*)(P + (size_t)nb*RV + 2048 + t*8);
#pragma unroll
    for (int i = 0; i < 2; ++i) {
      const int c = i*256 + t;
      const int row = c >> 3, k8 = c & 7;
      *(uint4*)(sX + row*64 + k8*8) =
          *(const uint4*)(xb + ((size_t)b*NB + nb + row)*DB + dt*64 + k8*8);
    }
    __syncthreads();
#pragma unroll 16
    for (int n = 0; n < 64; ++n) {
      bf16x4 pv = *(const bf16x4*)(sP + n*64 + r0);
      bf16x4 xv = *(const bf16x4*)(sX + n*64 + d0);
      float pf[4], xf[4];
#pragma unroll
      for (int i = 0; i < 4; ++i) { pf[i] = (float)pv[i]; xf[i] = (float)xv[i]; }
#pragma unroll
      for (int i = 0; i < 4; ++i)
#pragma unroll
        for (int j = 0; j < 4; ++j)
          acc[i][j] = fmaf(pf[i], xf[j], acc[i][j]);
    }
    __syncthreads();
  }
  float* Ob = O + ((size_t)b*64)*DB + dt*64;
#pragma unroll
  for (int i = 0; i < 4; ++i)
#pragma unroll
    for (int j = 0; j < 4; ++j)
      atomicAdd(&Ob[(size_t)(r0+i)*DB + d0 + j], acc[i][j]);
}

// MFMA attention: per block one (b,h) x 128 Q-rows. S = Q.Klow^T (16x16x32
// MFMAs), softmax in-reg (16-lane shfl reduce per C-row), P via per-wave
// swizzled LDS (C-layout -> A-layout), O = P.Vlow. Klow/Vlow staged bf16.
__global__ __launch_bounds__(256, 2) void attn_mfma(
    const bf16* Q, const float* __restrict__ Klow,
    const float* __restrict__ Vlow, bf16* AO) {
  const int bh = blockIdx.x, b = bh >> 4, h = bh & 15;
  const int n0 = blockIdx.y * 128;

  __shared__ bf16 sQ[128*64];     // 16 KiB, gemm-swizzled
  __shared__ bf16 sKb[64*64];     // 8 KiB  [r][d] swizzled
  __shared__ bf16 sVt[64*64];     // 8 KiB  [d][r] swizzled (transposed)
  __shared__ bf16 sP[4][32*64];   // 16 KiB, per-wave

  const int t = threadIdx.x;
  const int lane = t & 63;
  const int w = t >> 6;
  const int lr = lane & 15;
  const int quad = lane >> 4;

  // stage Q tile: rows n0..n0+127, cols h*64..h*64+63
#pragma unroll
  for (int i = 0; i < 4; ++i) {
    const int c = i*256 + t;
    const int row = c >> 3, j = c & 7;
    const uint4 v = *(const uint4*)(Q + ((size_t)b*NB + n0 + row)*DB + h*64 + j*8);
    *(uint4*)(sQ + (row*8 + (j ^ (row & 7)))*8) = v;
  }
  // stage Klow -> sKb (bf16, [r][d] swizzled) and Vlow -> sVt ([d][r])
  {
    const int r = t >> 2, c0 = (t & 3) * 16;
    const float* kb = Klow + (size_t)(b*64 + r)*DB + h*64 + c0;
    const float* vb = Vlow + (size_t)(b*64 + r)*DB + h*64 + c0;
    float kf[16], vf[16];
#pragma unroll
    for (int i = 0; i < 4; ++i) {
      *(f32x4*)(kf + i*4) = *(const f32x4*)(kb + i*4);
      *(f32x4*)(vf + i*4) = *(const f32x4*)(vb + i*4);
    }
#pragma unroll
    for (int cc = 0; cc < 2; ++cc) {
      bf16x8 pk;
#pragma unroll
      for (int j2 = 0; j2 < 8; ++j2) pk[j2] = (bf16)kf[cc*8 + j2];
      const int ch = (c0 >> 3) + cc;
      *(bf16x8*)(sKb + (r*8 + (ch ^ (r & 7)))*8) = pk;
    }
#pragma unroll
    for (int j2 = 0; j2 < 16; ++j2) {
      const int d = c0 + j2;
      sVt[d*64 + (((r >> 3) ^ (d & 7))*8) + (r & 7)] = (bf16)vf[j2];
    }
  }
  __syncthreads();

  // S = Q . Klow^T   (per wave: 32 rows, full r=64)
  f32x4 accS[2][4] = {};
#pragma unroll
  for (int ks = 0; ks < 2; ++ks) {
    const int kc = ks*4 + quad;
    bf16x8 af[2], bv[4];
#pragma unroll
    for (int mi = 0; mi < 2; ++mi) {
      const int m = w*32 + mi*16 + lr;
      af[mi] = *(const bf16x8*)(sQ + (m*8 + (kc ^ (m & 7)))*8);
    }
#pragma unroll
    for (int ni = 0; ni < 4; ++ni) {
      const int r = ni*16 + lr;
      bv[ni] = *(const bf16x8*)(sKb + (r*8 + (kc ^ (r & 7)))*8);
    }
#pragma unroll
    for (int mi = 0; mi < 2; ++mi)
#pragma unroll
      for (int ni = 0; ni < 4; ++ni)
        accS[mi][ni] = __builtin_amdgcn_mfma_f32_16x16x32_bf16(
            af[mi], bv[ni], accS[mi][ni], 0, 0, 0);
  }

  // softmax over r (C-layout: row=quad*4+rg local, col r=ni*16+lr)
  float inv_[2][4];
#pragma unroll
  for (int mi = 0; mi < 2; ++mi)
#pragma unroll
    for (int rg = 0; rg < 4; ++rg) {
      float mv = -3.0e38f;
#pragma unroll
      for (int ni = 0; ni < 4; ++ni) mv = fmaxf(mv, accS[mi][ni][rg]);
#pragma unroll
      for (int d = 1; d < 16; d <<= 1) mv = fmaxf(mv, __shfl_xor(mv, d));
      float sum = 0.0f;
#pragma unroll
      for (int ni = 0; ni < 4; ++ni) {
        const float p = __expf((accS[mi][ni][rg] - mv) * 0.125f);
        accS[mi][ni][rg] = p;
        sum += p;
      }
#pragma unroll
      for (int d = 1; d < 16; d <<= 1) sum += __shfl_xor(sum, d);
      inv_[mi][rg] = 1.0f / sum;   // applied at O-write (PV is linear)
    }

  // P: C-layout -> A-layout via per-wave swizzled LDS (no barrier needed)
  bf16* myP = sP[w];
#pragma unroll
  for (int mi = 0; mi < 2; ++mi)
#pragma unroll
    for (int ni = 0; ni < 4; ++ni)
#pragma unroll
      for (int rg = 0; rg < 4; ++rg) {
        const int row = mi*16 + quad*4 + rg;
        const int col = ni*16 + lr;
        myP[row*64 + ((col >> 3) ^ (row & 7))*8 + (col & 7)] = (bf16)accS[mi][ni][rg];
      }

  // O = P . Vlow   (gemm-NT against sVt[d][r])
  f32x4 accO[2][4] = {};
#pragma unroll
  for (int ks = 0; ks < 2; ++ks) {
    const int kc = ks*4 + quad;
    bf16x8 ap[2], bvv[4];
#pragma unroll
    for (int mi = 0; mi < 2; ++mi) {
      const int m = mi*16 + lr;
      ap[mi] = *(const bf16x8*)(myP + (m*8 + (kc ^ (m & 7)))*8);
    }
#pragma unroll
    for (int di = 0; di < 4; ++di) {
      const int d = di*16 + lr;
      bvv[di] = *(const bf16x8*)(sVt + (d*8 + (kc ^ (d & 7)))*8);
    }
#pragma unroll
    for (int mi = 0; mi < 2; ++mi)
#pragma unroll
      for (int di = 0; di < 4; ++di)
        accO[mi][di] = __builtin_amdgcn_mfma_f32_16x16x32_bf16(
            ap[mi], bvv[di], accO[mi][di], 0, 0, 0);
  }

  // write O (AO may alias Q: all global Q reads happened before the barrier)
#pragma unroll
  for (int mi = 0; mi < 2; ++mi)
#pragma unroll
    for (int rg = 0; rg < 4; ++rg) {
      const int n = n0 + w*32 + mi*16 + quad*4 + rg;
      const float iv = inv_[mi][rg];
      bf16* op = AO + ((size_t)b*NB + n)*DB + h*64;
#pragma unroll
      for (int di = 0; di < 4; ++di)
        op[di*16 + lr] = (bf16)(accO[mi][di][rg] * iv);
    }
}

extern "C" void kernel_launch(void* const* d_in, const int* in_sizes, int n_in,
                              void* d_out, int out_size, void* d_ws, size_t ws_size,
                              hipStream_t stream) {
  char* ws = (char*)d_ws;
  const size_t MiB = 1024*1024;
  int*   flag = (int*)ws;
  float* Klow = (float*)(ws + 1*MiB);
  float* Vlow = (float*)(ws + 2*MiB);
  float* xEf  = (float*)(ws + 3*MiB);
  float* xFf  = (float*)(ws + 4*MiB);
  bf16*  xEb  = (bf16*)(ws + 5*MiB);
  bf16*  xFb  = (bf16*)(ws + 5*MiB + 512*1024);
  bf16*  Wqb  = (bf16*)(ws + 7*MiB);
  bf16*  Wkb  = (bf16*)(ws + 9*MiB);
  bf16*  Wvb  = (bf16*)(ws + 11*MiB);
  bf16*  Wob  = (bf16*)(ws + 13*MiB);
  bf16*  bob  = (bf16*)(ws + 15*MiB);
  bf16*  Eb   = (bf16*)(ws + 16*MiB);
  bf16*  Fmb  = (bf16*)(ws + 17*MiB);
  bf16*  xb   = (bf16*)(ws + 20*MiB);
  bf16*  S0   = (bf16*)(ws + 52*MiB);

  detect_dtype<<<1, 256, 0, stream>>>((const unsigned short*)d_in[0], flag);

  CvtArgs ca;
  bf16* dsts[8] = {xb, Wqb, Wkb, Wvb, Wob, bob, Eb, Fmb};
  int   ns[8]   = {16777216, 1048576, 1048576, 1048576, 1048576, 1024, 262144, 262144};
  int off = 0;
  for (int i = 0; i < 8; ++i) {
    ca.src[i] = d_in[i]; ca.dst[i] = dsts[i]; ca.n[i] = ns[i];
    ca.off[i] = off; off += (ns[i] + 2047) / 2048;
  }
  ca.off[8] = off;
  to_bf16_multi<<<dim3(off), 256, 0, stream>>>(ca, flag);

  zero_f4<<<dim3(512), 256, 0, stream>>>(xEf);   // zeros xEf+xFf

  lowrank_xe<<<dim3(64, 8, 2), 256, 0, stream>>>(Eb, Fmb, xb, xEf, xFf);
  cvt_f32_bf16<<<dim3(256), 256, 0, stream>>>(xEf, xEb, 524288);  // xEf+xFf

  GemmArgs ka;                       // Klow = xE @ Wk^T ; Vlow = xF @ Wv^T
  ka.A = xEb; ka.B = Wkb; ka.C = Klow; ka.bias = nullptr;
  ka.oflag = nullptr; ka.force_f32 = 1;
  ka.M = 256; ka.N = DB; ka.K = DB;
  gemm_nt<<<dim3(8, 2), 256, 0, stream>>>(ka);
  ka.A = xFb; ka.B = Wvb; ka.C = Vlow;
  gemm_nt<<<dim3(8, 2), 256, 0, stream>>>(ka);

  GemmArgs qa;                       // Q = x @ Wq^T
  qa.A = xb; qa.B = Wqb; qa.C = S0; qa.bias = nullptr;
  qa.oflag = nullptr; qa.force_f32 = 0;
  qa.M = MB; qa.N = DB; qa.K = DB;
  gemm_nt<<<dim3(8, 128), 256, 0, stream>>>(qa);

  attn_mfma<<<dim3(64, 32), 256, 0, stream>>>(S0, Klow, Vlow, S0);

  GemmArgs oa;                       // out = AO @ Wo^T + bo
  oa.A = S0; oa.B = Wob; oa.C = d_out; oa.bias = bob;
  oa.oflag = flag; oa.force_f32 = 0;
  oa.M = MB; oa.N = DB; oa.K = DB;
  gemm_nt<<<dim3(8, 128), 256, 0, stream>>>(oa);
}